// Round 3
// baseline (741.575 us; speedup 1.0000x reference)
//
#include <hip/hip_runtime.h>

static constexpr int KC   = 9;   // kernel bins
static constexpr int CIN  = 32;  // input channels
static constexpr int CA   = 24;  // branch-a out channels
static constexpr int CB   = 8;   // branch-b out channels
static constexpr int COUT = 32;  // CA + CB
static constexpr int WPB  = 8;   // waves (output points) per block
static constexpr int TPB  = WPB * 64;  // 512 threads

// ---------------------------------------------------------------------------
// Kernel 1: CSR row pointer from sorted neighbors_out_index.
// ---------------------------------------------------------------------------
__global__ void build_rowptr(const int* __restrict__ oidx, int* __restrict__ rp,
                             int E, int nout) {
    int e = blockIdx.x * blockDim.x + threadIdx.x;
    if (e >= E) return;
    int cur  = oidx[e];
    int prev = (e == 0) ? -1 : oidx[e - 1];
    for (int id = prev + 1; id <= cur; ++id) rp[id] = e;
    if (e == E - 1) {
        for (int id = cur + 1; id <= nout; ++id) rp[id] = E;
    }
}

// ---------------------------------------------------------------------------
// Kernel 2: pack W_a [9][32][24], W_b [9][32][8] into Wt [f][k][c] (f-major)
// so the fused kernel can stage it to LDS and read it conflict-free.
// ---------------------------------------------------------------------------
__global__ void pack_weights(const float* __restrict__ Wa,
                             const float* __restrict__ Wb,
                             float* __restrict__ Wt) {
    int t = blockIdx.x * blockDim.x + threadIdx.x;
    if (t >= COUT * KC * CIN) return;
    int c = t & (CIN - 1);
    int k = (t >> 5) % KC;
    int f = t / (KC * CIN);
    Wt[t] = (f < CA) ? Wa[(k * CIN + c) * CA + f]
                     : Wb[(k * CIN + c) * CB + (f - CA)];
}

// ---------------------------------------------------------------------------
// Kernel 3: fused edge accumulation + dual matmul epilogue.
// One wave per output point; 8 waves per 512-thread block.
// Weights live in LDS (staged once per block, [f][k][c] layout ->
// ds_read_b32 with bank==c, conflict-free, single-base + imm offsets).
// ---------------------------------------------------------------------------
__global__ __launch_bounds__(TPB) void fused_conv(
    const float* __restrict__ feats, const float* __restrict__ importance,
    const float* __restrict__ Wt, const float* __restrict__ ba,
    const float* __restrict__ bb,
    const int* __restrict__ nidx, const int* __restrict__ nkidx,
    const int* __restrict__ rp,
    float* __restrict__ outf, float* __restrict__ outimp, int nout)
{
    __shared__ float sW[COUT * KC * CIN];   // 36864 B, layout [f][k][c]
    __shared__ float sA[WPB][KC * CIN];     // 9216 B
    __shared__ float sB[WPB][KC * CIN];     // 9216 B
    __shared__ int   sIdx[WPB][72];         // 64 + 8 zero pad
    __shared__ int   sKk [WPB][72];
    __shared__ float sImp[WPB][72];

    const int wave = threadIdx.x >> 6;
    const int lane = threadIdx.x & 63;
    const int c    = lane & 31;
    const int h    = lane >> 5;
    const int n    = blockIdx.x * WPB + wave;

    // stage weights to LDS (coalesced float4) + zero S tiles + metadata pads
    {
        const float4* src = reinterpret_cast<const float4*>(Wt);
        float4*       dst = reinterpret_cast<float4*>(sW);
        for (int i = threadIdx.x; i < COUT * KC * CIN / 4; i += TPB) dst[i] = src[i];
        float* pA = &sA[0][0];
        float* pB = &sB[0][0];
        for (int i = threadIdx.x; i < WPB * KC * CIN; i += TPB) {
            pA[i] = 0.f;
            pB[i] = 0.f;
        }
        int*   pI = &sIdx[0][0];
        int*   pK = &sKk[0][0];
        float* pM = &sImp[0][0];
        for (int i = threadIdx.x; i < WPB * 72; i += TPB) {
            pI[i] = 0; pK[i] = 0; pM[i] = 0.f;
        }
    }
    __syncthreads();

    int start = 0, end = 0;
    if (n < nout) { start = rp[n]; end = rp[n + 1]; }

    float accImp = 0.f;
    for (int base = start; base < end; base += 64) {
        int cnt = end - base; if (cnt > 64) cnt = 64;

        // cooperative metadata load: lane j <-> edge base+j; invalid lanes
        // store zeros so the predicated main loop can read them blindly.
        int idxv = 0, kkv = 0; float impv = 0.f;
        if (lane < cnt) {
            int j = base + lane;
            idxv = nidx[j];
            kkv  = nkidx[j];
            impv = importance[idxv];
        }
        accImp += impv;
        sIdx[wave][lane] = idxv;
        sKk [wave][lane] = kkv;
        sImp[wave][lane] = impv;
        // same-wave LDS RAW: compiler inserts lgkmcnt waits

        // fully predicated: 4 edges per half-wave per iteration, no serial tail
        for (int t = h; t < cnt; t += 8) {
            int   i0 = sIdx[wave][t],     i1 = sIdx[wave][t + 2];
            int   i2 = sIdx[wave][t + 4], i3 = sIdx[wave][t + 6];
            int   k0 = sKk[wave][t],      k1 = sKk[wave][t + 2];
            int   k2 = sKk[wave][t + 4],  k3 = sKk[wave][t + 6];
            float m0 = sImp[wave][t],     m1 = sImp[wave][t + 2];
            float m2 = sImp[wave][t + 4], m3 = sImp[wave][t + 6];
            // 4 independent coalesced row gathers in flight
            float f0 = feats[(size_t)i0 * CIN + c];
            float f1 = feats[(size_t)i1 * CIN + c];
            float f2 = feats[(size_t)i2 * CIN + c];
            float f3 = feats[(size_t)i3 * CIN + c];
            // mask out-of-range edges (their kk==0, imp==0 already)
            if (t + 2 >= cnt) f1 = 0.f;
            if (t + 4 >= cnt) f2 = 0.f;
            if (t + 6 >= cnt) f3 = 0.f;
            atomicAdd(&sA[wave][k0 * CIN + c], f0);
            atomicAdd(&sB[wave][k0 * CIN + c], f0 * m0);
            atomicAdd(&sA[wave][k1 * CIN + c], f1);
            atomicAdd(&sB[wave][k1 * CIN + c], f1 * m1);
            atomicAdd(&sA[wave][k2 * CIN + c], f2);
            atomicAdd(&sB[wave][k2 * CIN + c], f2 * m2);
            atomicAdd(&sA[wave][k3 * CIN + c], f3);
            atomicAdd(&sB[wave][k3 * CIN + c], f3 * m3);
        }
    }
    if (n >= nout) return;

    // total importance: lanes hold disjoint partial sums -> reduce all 64
    float impTot = accImp;
#pragma unroll
    for (int m = 1; m < 64; m <<= 1) impTot += __shfl_xor(impTot, m, 64);
    float denom = impTot > 0.f ? impTot : 1.f;

    // pull this lane's channel column of S into registers
    float a1[KC], a2[KC];
#pragma unroll
    for (int k = 0; k < KC; ++k) {
        float a = sA[wave][k * CIN + c];
        float b = sB[wave][k * CIN + c];
        a1[k] = a;            // features h*16 + 0..7  (always branch-a)
        a2[k] = h ? b : a;    // features h*16 + 8..15 (h1: 24..31 -> branch-b)
    }

    // partial products from LDS weights: p[j] = sum_k acc*W[h*16+j][k][c]
    // addr(j,k) = base + j*1152B + k*128B -> one base VGPR + imm offsets,
    // bank == c for every read -> conflict-free (2-way across halves).
    const float* wp = sW + (h * 16) * KC * CIN + c;
    float p[16];
#pragma unroll
    for (int j = 0; j < 16; ++j) {
        float acc = 0.f;
#pragma unroll
        for (int k = 0; k < KC; ++k) {
            float w = wp[j * KC * CIN + k * CIN];
            acc = fmaf((j < 8) ? a1[k] : a2[k], w, acc);
        }
        p[j] = acc;
    }

    // fold-and-halve transpose reduce: 16 values over 32 channel lanes
    const int b0 = c & 1, b1 = (c >> 1) & 1, b2 = (c >> 2) & 1, b3 = (c >> 3) & 1;
    float v8[8];
#pragma unroll
    for (int q = 0; q < 8; ++q) {
        float kept = b0 ? p[2 * q + 1] : p[2 * q];
        float giv  = b0 ? p[2 * q]     : p[2 * q + 1];
        v8[q] = kept + __shfl_xor(giv, 1, 64);
    }
    float v4[4];
#pragma unroll
    for (int q = 0; q < 4; ++q) {
        float kept = b1 ? v8[2 * q + 1] : v8[2 * q];
        float giv  = b1 ? v8[2 * q]     : v8[2 * q + 1];
        v4[q] = kept + __shfl_xor(giv, 2, 64);
    }
    float v2[2];
#pragma unroll
    for (int q = 0; q < 2; ++q) {
        float kept = b2 ? v4[2 * q + 1] : v4[2 * q];
        float giv  = b2 ? v4[2 * q]     : v4[2 * q + 1];
        v2[q] = kept + __shfl_xor(giv, 4, 64);
    }
    float kept = b3 ? v2[1] : v2[0];
    float giv  = b3 ? v2[0] : v2[1];
    float v1 = kept + __shfl_xor(giv, 8, 64);
    v1 += __shfl_xor(v1, 16, 64);
    // lane c now holds the full sum for feature (c & 15) of its half

    if (c < 16) {
        int   f = h * 16 + c;
        float res;
        if (f < CA) res = v1 + ba[f];
        else        res = v1 / denom + bb[f - CA];
        outf[n * COUT + f] = fmaxf(res, 0.f);
    }
    if (lane == 0) outimp[n] = impTot;
}

// ---------------------------------------------------------------------------
extern "C" void kernel_launch(void* const* d_in, const int* in_sizes, int n_in,
                              void* d_out, int out_size, void* d_ws, size_t ws_size,
                              hipStream_t stream) {
    const float* feats      = (const float*)d_in[0];
    const float* importance = (const float*)d_in[1];
    const float* Wa         = (const float*)d_in[2];
    const float* ba         = (const float*)d_in[3];
    const float* Wb         = (const float*)d_in[4];
    const float* bb         = (const float*)d_in[5];
    const int*   nidx       = (const int*)d_in[6];
    const int*   nkidx      = (const int*)d_in[7];
    const int*   noidx      = (const int*)d_in[8];

    const int E    = in_sizes[6];
    const int nout = out_size / (COUT + 1);

    float* outf   = (float*)d_out;
    float* outimp = outf + (size_t)nout * COUT;

    int*   rp = (int*)d_ws;
    size_t rp_bytes = ((size_t)(nout + 1) * sizeof(int) + 255) & ~(size_t)255;
    float* Wt = (float*)((char*)d_ws + rp_bytes);

    build_rowptr<<<(E + 255) / 256, 256, 0, stream>>>(noidx, rp, E, nout);
    pack_weights<<<(COUT * KC * CIN + 255) / 256, 256, 0, stream>>>(Wa, Wb, Wt);
    fused_conv<<<(nout + WPB - 1) / WPB, TPB, 0, stream>>>(
        feats, importance, Wt, ba, bb, nidx, nkidx, rp, outf, outimp, nout);
}